// Round 5
// baseline (422.673 us; speedup 1.0000x reference)
//
#include <hip/hip_runtime.h>
#include <hip/hip_bf16.h>
#include <hip/hip_cooperative_groups.h>

namespace cg = cooperative_groups;

// GrantGCN: out = [h, A h] @ W2^T + b2, h = relu([x, A x] @ W1^T + b1)
// A built from edges with numpy semantics:
//   adj[src,dst] = w   (scatter-SET: last edge in order wins per (src,dst))
//   adj[dst,src] += w  (scatter-ADD: all edges accumulate)
// Round-4: the 7-dispatch pipeline was dominated by serial launch/latency
// overhead (no dispatch >20us, total 123us). Collapse everything into ONE
// cooperative kernel with grid.sync() between phases:
//   0: init hash tables + deg
//   1: hash insert (winner = max edge id per (src,dst)) + degree count
//      (every edge gets 2 CSR slots unconditionally; losers get val=0)
//   2: exclusive scan of deg (block 0)
//   3: CSR scatter (winner lookup decides val vs 0)
//   4: fusedA: wave-per-node gather y1=(A x)[n] + dense1 + relu -> h
//   5: fusedB: wave-per-node gather y2=(A h)[n] + dense2 -> out

#define NN    8192
#define NE    131072
#define XD    32
#define HID   64
#define NC    40
#define TBL   (1u << 18)
#define TMASK (TBL - 1u)
#define EMPTYK 0xFFFFFFFFu
#define NBLK  512
#define NT    (NBLK * 256)   // 131072 == NE

struct Params {
    const int*   src;
    const int*   dst;
    const float* w;
    const float* x;
    const float* W1;
    const float* b1;
    const float* W2;
    const float* b2;
    unsigned*    keys;
    unsigned*    vals;
    unsigned*    deg;
    unsigned*    row_start;
    unsigned*    cur;
    int*         col;
    float*       val;
    float*       h;
    float*       out;
};

__device__ __forceinline__ unsigned hashk(unsigned k) {
    return (k * 2654435761u) & TMASK;
}

__global__ __launch_bounds__(256, 2) void mega(Params p) {
    cg::grid_group grid = cg::this_grid();
    const int t   = threadIdx.x;
    const int tid = blockIdx.x * 256 + t;

    // ---- phase 0: init keys (0xFF), vals (0), deg (0) ----
    p.keys[tid]      = EMPTYK;
    p.keys[tid + NT] = EMPTYK;
    p.vals[tid]      = 0u;
    p.vals[tid + NT] = 0u;
    if (tid < NN) p.deg[tid] = 0u;
    grid.sync();

    // ---- phase 1: hash insert + degree count (tid == edge id) ----
    {
        const int e = tid;
        const int s = p.src[e], d = p.dst[e];
        const unsigned key = (unsigned)s * (unsigned)NN + (unsigned)d;
        unsigned hh = hashk(key);
        while (true) {
            unsigned old = atomicCAS(&p.keys[hh], EMPTYK, key);
            if (old == EMPTYK || old == key) {
                atomicMax(&p.vals[hh], (unsigned)(e + 1));
                break;
            }
            hh = (hh + 1u) & TMASK;
        }
        atomicAdd(&p.deg[d], 1u);   // add-direction slot (always)
        atomicAdd(&p.deg[s], 1u);   // set-direction slot (always; loser -> val 0)
    }
    grid.sync();

    // ---- phase 2: exclusive scan of deg (block 0 only) ----
    __shared__ unsigned part[256];
    if (blockIdx.x == 0) {
        unsigned sum = 0;
        for (int i = 0; i < 32; ++i) sum += p.deg[t * 32 + i];
        part[t] = sum;
        __syncthreads();
        for (int off = 1; off < 256; off <<= 1) {
            unsigned v = 0;
            if (t >= off) v = part[t - off];
            __syncthreads();
            if (t >= off) part[t] += v;
            __syncthreads();
        }
        unsigned base = (t > 0) ? part[t - 1] : 0u;
        for (int i = 0; i < 32; ++i) {
            unsigned dg = p.deg[t * 32 + i];
            p.row_start[t * 32 + i] = base;
            p.cur[t * 32 + i] = base;
            base += dg;
        }
        if (t == 255) p.row_start[NN] = base;   // == 2*NE
    }
    grid.sync();

    // ---- phase 3: CSR scatter (winner lookup) ----
    {
        const int e = tid;
        const int s = p.src[e], d = p.dst[e];
        const float we = p.w[e];
        const unsigned key = (unsigned)s * (unsigned)NN + (unsigned)d;
        unsigned hh = hashk(key);
        while (p.keys[hh] != key) hh = (hh + 1u) & TMASK;
        const bool win = (p.vals[hh] == (unsigned)(e + 1));
        unsigned q1 = atomicAdd(&p.cur[d], 1u);
        p.col[q1] = s; p.val[q1] = we;
        unsigned q2 = atomicAdd(&p.cur[s], 1u);
        p.col[q2] = d; p.val[q2] = win ? we : 0.0f;
    }
    grid.sync();

    // ---- phase 4: fusedA (wave per node, 4 nodes per wave) ----
    __shared__ float4 gcA[4][16];   // per wave: quads 0..7 = x row, 8..15 = y1
    const int g4 = t >> 6;
    const int l  = t & 63;
    const int wv = blockIdx.x * 4 + g4;       // 0..2047
    const float4* x4  = (const float4*)p.x;
    const float4* w14 = (const float4*)p.W1;
    {
        const int eq = l >> 3, fq = l & 7;
        for (int it = 0; it < 4; ++it) {
            const int n = wv * 4 + it;        // 0..8191
            const unsigned b = p.row_start[n], e = p.row_start[n + 1];
            float4 acc = make_float4(0.f, 0.f, 0.f, 0.f);
            for (unsigned i = b + eq; i < e; i += 8) {
                const int c = p.col[i];
                const float v = p.val[i];
                const float4 xv = x4[c * 8 + fq];
                acc.x += v * xv.x; acc.y += v * xv.y;
                acc.z += v * xv.z; acc.w += v * xv.w;
            }
#pragma unroll
            for (int m = 8; m < 64; m <<= 1) {
                acc.x += __shfl_xor(acc.x, m);
                acc.y += __shfl_xor(acc.y, m);
                acc.z += __shfl_xor(acc.z, m);
                acc.w += __shfl_xor(acc.w, m);
            }
            if (l < 8) {
                gcA[g4][l]     = x4[n * 8 + l];
                gcA[g4][8 + l] = acc;          // lane l holds sum for fq == l
            }
            __syncthreads();
            float a = p.b1[l];
#pragma unroll
            for (int j = 0; j < 16; ++j) {
                const float4 gv = gcA[g4][j];
                const float4 wvv = w14[l * 16 + j];
                a += gv.x * wvv.x + gv.y * wvv.y + gv.z * wvv.z + gv.w * wvv.w;
            }
            p.h[n * HID + l] = fmaxf(a, 0.f);
            __syncthreads();
        }
    }
    grid.sync();

    // ---- phase 5: fusedB ----
    __shared__ float4 gcB[4][32];   // per wave: quads 0..15 = h row, 16..31 = y2
    const float4* h4  = (const float4*)p.h;
    const float4* w24 = (const float4*)p.W2;
    {
        const int eq = l >> 4, fq = l & 15;
        for (int it = 0; it < 4; ++it) {
            const int n = wv * 4 + it;
            const unsigned b = p.row_start[n], e = p.row_start[n + 1];
            float4 acc = make_float4(0.f, 0.f, 0.f, 0.f);
            for (unsigned i = b + eq; i < e; i += 4) {
                const int c = p.col[i];
                const float v = p.val[i];
                const float4 hv = h4[c * 16 + fq];
                acc.x += v * hv.x; acc.y += v * hv.y;
                acc.z += v * hv.z; acc.w += v * hv.w;
            }
#pragma unroll
            for (int m = 16; m < 64; m <<= 1) {
                acc.x += __shfl_xor(acc.x, m);
                acc.y += __shfl_xor(acc.y, m);
                acc.z += __shfl_xor(acc.z, m);
                acc.w += __shfl_xor(acc.w, m);
            }
            if (l < 16) {
                gcB[g4][l]      = h4[n * 16 + l];
                gcB[g4][16 + l] = acc;         // lane l holds sum for fq == l
            }
            __syncthreads();
            if (l < NC) {
                float a = p.b2[l];
#pragma unroll
                for (int j = 0; j < 32; ++j) {
                    const float4 gv = gcB[g4][j];
                    const float4 wvv = w24[l * 32 + j];
                    a += gv.x * wvv.x + gv.y * wvv.y + gv.z * wvv.z + gv.w * wvv.w;
                }
                p.out[n * NC + l] = a;
            }
            __syncthreads();
        }
    }
}

extern "C" void kernel_launch(void* const* d_in, const int* in_sizes, int n_in,
                              void* d_out, int out_size, void* d_ws, size_t ws_size,
                              hipStream_t stream) {
    char* ws = (char*)d_ws;
    Params p;
    p.src = (const int*)d_in[1];
    p.dst = (const int*)d_in[1] + NE;
    p.w   = (const float*)d_in[2];
    p.x   = (const float*)d_in[0];
    // d_in[3] is k (always 2)
    p.W1  = (const float*)d_in[4];
    p.b1  = (const float*)d_in[5];
    p.W2  = (const float*)d_in[6];
    p.b2  = (const float*)d_in[7];
    p.keys      = (unsigned*)(ws + (0 << 20));                  // 1 MiB
    p.vals      = (unsigned*)(ws + (1 << 20));                  // 1 MiB
    p.col       = (int*)     (ws + (2 << 20));                  // 1 MiB (2*NE ints)
    p.val       = (float*)   (ws + (3 << 20));                  // 1 MiB
    p.deg       = (unsigned*)(ws + (4 << 20));                  // 32 KiB
    p.row_start = (unsigned*)(ws + (4 << 20) + (64 << 10));     // 32 KiB + 4
    p.cur       = (unsigned*)(ws + (4 << 20) + (128 << 10));    // 32 KiB
    p.h         = (float*)   (ws + (5 << 20));                  // 2 MiB
    p.out       = (float*)d_out;

    void* args[] = {&p};
    hipLaunchCooperativeKernel((const void*)mega, dim3(NBLK), dim3(256),
                               args, 0, stream);
}

// Round 7
// 114.945 us; speedup vs baseline: 3.6772x; 3.6772x over previous
//
#include <hip/hip_runtime.h>
#include <hip/hip_bf16.h>

// GrantGCN: out = [h, A h] @ W2^T + b2, h = relu([x, A x] @ W1^T + b1)
// A built from edges with numpy semantics:
//   adj[src,dst] = w   (scatter-SET: last edge in order wins per (src,dst))
//   adj[dst,src] += w  (scatter-ADD: all edges accumulate)
// Pipeline (6 dispatches; cooperative single-launch abandoned: round-5 showed
// low-occupancy serialization at 409us, round-6's 2048-block coop launch
// exceeded co-residency and failed):
//   1 init_tables   : keys<-0xFF, vals/deg<-0 (uint4 stores)
//   2 insert_count  : hash insert (winner = max edge id) + degree count
//                     (every edge contributes 2 CSR slots; losers get w=0)
//   3 scan_deg      : exclusive scan, single 1024-thread block
//   4 scatter       : winner probe; write packed uint2{col, w_bits}
//   5 fusedA        : wave/node gather y1=(A x)[n] + dense1 + relu -> h
//   6 fusedB        : wave/node gather y2=(A h)[n] + dense2 -> out

#define NN    8192
#define NE    131072
#define XD    32
#define HID   64
#define NC    40
#define TBL   (1u << 18)
#define TMASK (TBL - 1u)
#define EMPTYK 0xFFFFFFFFu

__device__ __forceinline__ unsigned hashk(unsigned k) {
    return (k * 2654435761u) & TMASK;
}

// keys <- 0xFF (TBL dwords), vals+deg <- 0 (TBL+NN dwords, contiguous)
#define K4  (TBL / 4)          // 65536 uint4
#define VD4 ((TBL + NN) / 4)   // 67584 uint4
__global__ void init_tables(uint4* __restrict__ keys, uint4* __restrict__ valsdeg) {
    int t = blockIdx.x * blockDim.x + threadIdx.x;
    if (t < K4)  keys[t]    = make_uint4(~0u, ~0u, ~0u, ~0u);
    if (t < VD4) valsdeg[t] = make_uint4(0u, 0u, 0u, 0u);
}

// hash insert (winner = max edge id per (src,dst)) + unconditional degree count
__global__ void insert_count(const int* __restrict__ src, const int* __restrict__ dst,
                             unsigned* __restrict__ keys, unsigned* __restrict__ vals,
                             unsigned* __restrict__ deg) {
    int e = blockIdx.x * blockDim.x + threadIdx.x;
    if (e >= NE) return;
    const int s = src[e], d = dst[e];
    const unsigned key = (unsigned)s * (unsigned)NN + (unsigned)d;
    unsigned h = hashk(key);
    while (true) {
        unsigned old = atomicCAS(&keys[h], EMPTYK, key);
        if (old == EMPTYK || old == key) {
            atomicMax(&vals[h], (unsigned)(e + 1));  // e+1 so 0 == "none"
            break;
        }
        h = (h + 1u) & TMASK;
    }
    atomicAdd(&deg[d], 1u);   // add-direction slot (always)
    atomicAdd(&deg[s], 1u);   // set-direction slot (always; loser -> w=0)
}

// exclusive prefix sum over 8192 degrees; single block of 1024 x 8 elems.
__global__ __launch_bounds__(1024) void scan_deg(const unsigned* __restrict__ deg,
                                                 unsigned* __restrict__ row_start,
                                                 unsigned* __restrict__ cur) {
    __shared__ unsigned sums[1024];
    int t = threadIdx.x;
    unsigned local[8];
    unsigned s = 0;
#pragma unroll
    for (int i = 0; i < 8; ++i) { local[i] = deg[t * 8 + i]; s += local[i]; }
    sums[t] = s;
    __syncthreads();
    for (int off = 1; off < 1024; off <<= 1) {
        unsigned v = 0;
        if (t >= off) v = sums[t - off];
        __syncthreads();
        if (t >= off) sums[t] += v;
        __syncthreads();
    }
    unsigned base = (t > 0) ? sums[t - 1] : 0u;
#pragma unroll
    for (int i = 0; i < 8; ++i) {
        row_start[t * 8 + i] = base;
        cur[t * 8 + i] = base;
        base += local[i];
    }
    if (t == 1023) row_start[NN] = base;   // == 2*NE
}

__global__ void scatter(const int* __restrict__ src, const int* __restrict__ dst,
                        const float* __restrict__ w,
                        const unsigned* __restrict__ keys, const unsigned* __restrict__ vals,
                        unsigned* __restrict__ cur, uint2* __restrict__ cv) {
    int e = blockIdx.x * blockDim.x + threadIdx.x;
    if (e >= NE) return;
    const int s = src[e], d = dst[e];
    const unsigned wb = __float_as_uint(w[e]);
    const unsigned key = (unsigned)s * (unsigned)NN + (unsigned)d;
    unsigned h = hashk(key);
    while (keys[h] != key) h = (h + 1u) & TMASK;
    const bool win = (vals[h] == (unsigned)(e + 1));
    const unsigned q1 = atomicAdd(&cur[d], 1u);
    cv[q1] = make_uint2((unsigned)s, wb);
    const unsigned q2 = atomicAdd(&cur[s], 1u);
    cv[q2] = make_uint2((unsigned)d, win ? wb : 0u);
}

// fusedA: one 64-lane wave per node. Lane = (edge-slot eq 0..7, feature-quad
// fq 0..7). Gather y1 = (A x)[n] as float4 per lane, xor-reduce over edge
// slots, stage concat(x_n, y1_n) in LDS, dense1+relu -> h (lane = hidden unit).
__global__ __launch_bounds__(256) void fusedA(const unsigned* __restrict__ row_start,
                                              const uint2* __restrict__ cv,
                                              const float* __restrict__ x,
                                              const float* __restrict__ W1,
                                              const float* __restrict__ b1,
                                              float* __restrict__ h) {
    __shared__ float4 gc[4][16];   // per node: quads 0..7 = x row, 8..15 = y1 row
    const int t = threadIdx.x;
    const int g = t >> 6;          // wave slot 0..3
    const int l = t & 63;
    const int n = blockIdx.x * 4 + g;
    const int eq = l >> 3;         // edge slot 0..7
    const int fq = l & 7;          // feature quad 0..7
    const float4* x4 = (const float4*)x;
    const unsigned b = row_start[n], e = row_start[n + 1];
    float4 acc = make_float4(0.f, 0.f, 0.f, 0.f);
    for (unsigned i = b + eq; i < e; i += 8) {
        const uint2 ce = cv[i];
        const float v = __uint_as_float(ce.y);
        const float4 xv = x4[ce.x * 8 + fq];
        acc.x += v * xv.x; acc.y += v * xv.y; acc.z += v * xv.z; acc.w += v * xv.w;
    }
#pragma unroll
    for (int m = 8; m < 64; m <<= 1) {
        acc.x += __shfl_xor(acc.x, m);
        acc.y += __shfl_xor(acc.y, m);
        acc.z += __shfl_xor(acc.z, m);
        acc.w += __shfl_xor(acc.w, m);
    }
    if (l < 8) {
        gc[g][l]     = x4[n * 8 + l];
        gc[g][8 + l] = acc;        // lane l holds the sum for fq == l
    }
    __syncthreads();
    // dense1: lane l = hidden unit l of node n
    const float4* w4 = (const float4*)&W1[l * (2 * XD)];
    float a = b1[l];
#pragma unroll
    for (int j = 0; j < 16; ++j) {
        const float4 gv = gc[g][j];
        const float4 wv = w4[j];
        a += gv.x * wv.x + gv.y * wv.y + gv.z * wv.z + gv.w * wv.w;
    }
    h[n * HID + l] = fmaxf(a, 0.f);
}

// fusedB: one 64-lane wave per node. Lane = (edge-slot eq 0..7, quad fq 0..7);
// each lane covers quads fq and fq+8 of the 16-quad h row (8-deep edge MLP).
__global__ __launch_bounds__(256) void fusedB(const unsigned* __restrict__ row_start,
                                              const uint2* __restrict__ cv,
                                              const float* __restrict__ h,
                                              const float* __restrict__ W2,
                                              const float* __restrict__ b2,
                                              float* __restrict__ out) {
    __shared__ float4 gc[4][32];   // per node: quads 0..15 = h row, 16..31 = y2 row
    const int t = threadIdx.x;
    const int g = t >> 6;
    const int l = t & 63;
    const int n = blockIdx.x * 4 + g;
    const int eq = l >> 3;         // edge slot 0..7
    const int fq = l & 7;          // feature quad 0..7 (covers fq and fq+8)
    const float4* h4 = (const float4*)h;
    const unsigned b = row_start[n], e = row_start[n + 1];
    float4 a0 = make_float4(0.f, 0.f, 0.f, 0.f);
    float4 a1 = make_float4(0.f, 0.f, 0.f, 0.f);
    for (unsigned i = b + eq; i < e; i += 8) {
        const uint2 ce = cv[i];
        const float v = __uint_as_float(ce.y);
        const float4 h0 = h4[ce.x * 16 + fq];
        const float4 h1 = h4[ce.x * 16 + fq + 8];
        a0.x += v * h0.x; a0.y += v * h0.y; a0.z += v * h0.z; a0.w += v * h0.w;
        a1.x += v * h1.x; a1.y += v * h1.y; a1.z += v * h1.z; a1.w += v * h1.w;
    }
#pragma unroll
    for (int m = 8; m < 64; m <<= 1) {
        a0.x += __shfl_xor(a0.x, m);
        a0.y += __shfl_xor(a0.y, m);
        a0.z += __shfl_xor(a0.z, m);
        a0.w += __shfl_xor(a0.w, m);
        a1.x += __shfl_xor(a1.x, m);
        a1.y += __shfl_xor(a1.y, m);
        a1.z += __shfl_xor(a1.z, m);
        a1.w += __shfl_xor(a1.w, m);
    }
    if (l < 8) {
        gc[g][16 + l]     = a0;    // y2 quads 0..7
        gc[g][24 + l]     = a1;    // y2 quads 8..15
    }
    if (l < 16) gc[g][l] = h4[n * 16 + l];
    __syncthreads();
    if (l < NC) {
        const float4* w4 = (const float4*)&W2[l * (2 * HID)];
        float a = b2[l];
#pragma unroll
        for (int j = 0; j < 32; ++j) {
            const float4 gv = gc[g][j];
            const float4 wv = w4[j];
            a += gv.x * wv.x + gv.y * wv.y + gv.z * wv.z + gv.w * wv.w;
        }
        out[n * NC + l] = a;
    }
}

extern "C" void kernel_launch(void* const* d_in, const int* in_sizes, int n_in,
                              void* d_out, int out_size, void* d_ws, size_t ws_size,
                              hipStream_t stream) {
    const float* x  = (const float*)d_in[0];
    const int*   ei = (const int*)d_in[1];
    const float* w  = (const float*)d_in[2];
    // d_in[3] is k (always 2)
    const float* W1 = (const float*)d_in[4];
    const float* b1 = (const float*)d_in[5];
    const float* W2 = (const float*)d_in[6];
    const float* b2 = (const float*)d_in[7];
    float* out = (float*)d_out;

    char* ws = (char*)d_ws;
    unsigned* keys      = (unsigned*)(ws + (0 << 20));               // 1 MiB
    unsigned* vals      = (unsigned*)(ws + (1 << 20));               // 1 MiB
    unsigned* deg       = (unsigned*)(ws + (2 << 20));               // 32 KiB (contiguous after vals)
    unsigned* row_start = (unsigned*)(ws + (2 << 20) + (64 << 10));  // 32 KiB + 4
    unsigned* cur       = (unsigned*)(ws + (2 << 20) + (128 << 10)); // 32 KiB
    uint2*    cv        = (uint2*)   (ws + (3 << 20));               // 2 MiB (2*NE uint2)
    float*    h         = (float*)   (ws + (5 << 20));               // 2 MiB

    const int* src = ei;        // edge_index[0, :]
    const int* dst = ei + NE;   // edge_index[1, :]

    init_tables<<<(VD4 + 255) / 256, 256, 0, stream>>>((uint4*)keys, (uint4*)vals);
    insert_count<<<NE / 256, 256, 0, stream>>>(src, dst, keys, vals, deg);
    scan_deg<<<1, 1024, 0, stream>>>(deg, row_start, cur);
    scatter<<<NE / 256, 256, 0, stream>>>(src, dst, w, keys, vals, cur, cv);
    fusedA<<<NN / 4, 256, 0, stream>>>(row_start, cv, x, W1, b1, h);
    fusedB<<<NN / 4, 256, 0, stream>>>(row_start, cv, h, W2, b2, out);
}

// Round 8
// 103.677 us; speedup vs baseline: 4.0768x; 1.1087x over previous
//
#include <hip/hip_runtime.h>
#include <hip/hip_bf16.h>

// GrantGCN: out = [h, A h] @ W2^T + b2, h = relu([x, A x] @ W1^T + b1)
// A built from edges with numpy semantics:
//   adj[src,dst] = w   (scatter-SET: last edge in order wins per (src,dst))
//   adj[dst,src] += w  (scatter-ADD: all edges accumulate)
// Round-8: padded-ELL adjacency (stride 96) kills the scan phase. 5 dispatches:
//   1 init    : keys<-0xFF, vals<-0, cnt<-0
//   2 build1  : hash insert (winner = max edge id) + write add-direction
//               entries {src,w} at ell[dst*96 + atomicAdd(cnt[dst])]
//   3 build2  : winner probe + write set-direction entries {dst, win?w:0}
//   4 fusedA  : wave/node gather y1=(A x)[n] + dense1 + relu -> h
//   5 fusedB  : wave/node gather y2=(A h)[n] + dense2 -> out
// Mean total degree 32 (Poisson); P(deg>=96) ~ 1e-18 -> stride 96 safe.

#define NN    8192
#define NE    131072
#define XD    32
#define HID   64
#define NC    40
#define ESTR  96          // ELL row stride (entries)
#define TBL   (1u << 18)
#define TMASK (TBL - 1u)
#define EMPTYK 0xFFFFFFFFu

__device__ __forceinline__ unsigned hashk(unsigned k) {
    return (k * 2654435761u) & TMASK;
}

// keys <- 0xFF (TBL dwords), vals+cnt <- 0 (TBL+NN dwords, contiguous)
#define KV4 ((TBL + TBL + NN) / 4)   // 133120 uint4 covering keys|vals|cnt
__global__ void init_tables(uint4* __restrict__ base) {
    int t = blockIdx.x * blockDim.x + threadIdx.x;
    if (t >= KV4) return;
    base[t] = (t < (int)(TBL / 4)) ? make_uint4(~0u, ~0u, ~0u, ~0u)
                                   : make_uint4(0u, 0u, 0u, 0u);
}

// hash insert (winner = max edge id per (src,dst)) + add-direction ELL write
__global__ void build1(const int* __restrict__ src, const int* __restrict__ dst,
                       const float* __restrict__ w,
                       unsigned* __restrict__ keys, unsigned* __restrict__ vals,
                       unsigned* __restrict__ cnt, uint2* __restrict__ ell) {
    int e = blockIdx.x * blockDim.x + threadIdx.x;
    if (e >= NE) return;
    const int s = src[e], d = dst[e];
    const unsigned key = (unsigned)s * (unsigned)NN + (unsigned)d;
    unsigned h = hashk(key);
    while (true) {
        unsigned old = atomicCAS(&keys[h], EMPTYK, key);
        if (old == EMPTYK || old == key) {
            atomicMax(&vals[h], (unsigned)(e + 1));  // e+1 so 0 == "none"
            break;
        }
        h = (h + 1u) & TMASK;
    }
    const unsigned q = atomicAdd(&cnt[d], 1u);
    ell[d * ESTR + q] = make_uint2((unsigned)s, __float_as_uint(w[e]));
}

// winner probe + set-direction ELL write (losers carry w=0)
__global__ void build2(const int* __restrict__ src, const int* __restrict__ dst,
                       const float* __restrict__ w,
                       const unsigned* __restrict__ keys, const unsigned* __restrict__ vals,
                       unsigned* __restrict__ cnt, uint2* __restrict__ ell) {
    int e = blockIdx.x * blockDim.x + threadIdx.x;
    if (e >= NE) return;
    const int s = src[e], d = dst[e];
    const unsigned key = (unsigned)s * (unsigned)NN + (unsigned)d;
    unsigned h = hashk(key);
    while (keys[h] != key) h = (h + 1u) & TMASK;
    const bool win = (vals[h] == (unsigned)(e + 1));
    const unsigned q = atomicAdd(&cnt[s], 1u);
    ell[s * ESTR + q] = make_uint2((unsigned)d, win ? __float_as_uint(w[e]) : 0u);
}

// fusedA: one 64-lane wave per node. Lane = (edge-slot eq 0..7, feature-quad
// fq 0..7). Gather y1 = (A x)[n] as float4 per lane, xor-reduce over edge
// slots, stage concat(x_n, y1_n) in LDS, dense1+relu -> h (lane = hidden unit).
__global__ __launch_bounds__(256) void fusedA(const unsigned* __restrict__ cnt,
                                              const uint2* __restrict__ ell,
                                              const float* __restrict__ x,
                                              const float* __restrict__ W1,
                                              const float* __restrict__ b1,
                                              float* __restrict__ h) {
    __shared__ float4 gc[4][16];   // per node: quads 0..7 = x row, 8..15 = y1 row
    const int t = threadIdx.x;
    const int g = t >> 6;          // wave slot 0..3
    const int l = t & 63;
    const int n = blockIdx.x * 4 + g;
    const int eq = l >> 3;         // edge slot 0..7
    const int fq = l & 7;          // feature quad 0..7
    const float4* x4 = (const float4*)x;
    const unsigned m = cnt[n];
    const uint2* row = &ell[n * ESTR];
    float4 acc = make_float4(0.f, 0.f, 0.f, 0.f);
    for (unsigned i = eq; i < m; i += 8) {
        const uint2 ce = row[i];
        const float v = __uint_as_float(ce.y);
        const float4 xv = x4[ce.x * 8 + fq];
        acc.x += v * xv.x; acc.y += v * xv.y; acc.z += v * xv.z; acc.w += v * xv.w;
    }
#pragma unroll
    for (int mm = 8; mm < 64; mm <<= 1) {
        acc.x += __shfl_xor(acc.x, mm);
        acc.y += __shfl_xor(acc.y, mm);
        acc.z += __shfl_xor(acc.z, mm);
        acc.w += __shfl_xor(acc.w, mm);
    }
    if (l < 8) {
        gc[g][l]     = x4[n * 8 + l];
        gc[g][8 + l] = acc;        // lane l holds the sum for fq == l
    }
    __syncthreads();
    // dense1: lane l = hidden unit l of node n
    const float4* w4 = (const float4*)&W1[l * (2 * XD)];
    float a = b1[l];
#pragma unroll
    for (int j = 0; j < 16; ++j) {
        const float4 gv = gc[g][j];
        const float4 wv = w4[j];
        a += gv.x * wv.x + gv.y * wv.y + gv.z * wv.z + gv.w * wv.w;
    }
    h[n * HID + l] = fmaxf(a, 0.f);
}

// fusedB: one 64-lane wave per node. Lane = (edge-slot eq 0..7, quad fq 0..7);
// each lane covers quads fq and fq+8 of the 16-quad h row.
__global__ __launch_bounds__(256) void fusedB(const unsigned* __restrict__ cnt,
                                              const uint2* __restrict__ ell,
                                              const float* __restrict__ h,
                                              const float* __restrict__ W2,
                                              const float* __restrict__ b2,
                                              float* __restrict__ out) {
    __shared__ float4 gc[4][32];   // per node: quads 0..15 = h row, 16..31 = y2 row
    const int t = threadIdx.x;
    const int g = t >> 6;
    const int l = t & 63;
    const int n = blockIdx.x * 4 + g;
    const int eq = l >> 3;         // edge slot 0..7
    const int fq = l & 7;          // feature quad 0..7 (covers fq and fq+8)
    const float4* h4 = (const float4*)h;
    const unsigned m = cnt[n];
    const uint2* row = &ell[n * ESTR];
    float4 a0 = make_float4(0.f, 0.f, 0.f, 0.f);
    float4 a1 = make_float4(0.f, 0.f, 0.f, 0.f);
    for (unsigned i = eq; i < m; i += 8) {
        const uint2 ce = row[i];
        const float v = __uint_as_float(ce.y);
        const float4 h0 = h4[ce.x * 16 + fq];
        const float4 h1 = h4[ce.x * 16 + fq + 8];
        a0.x += v * h0.x; a0.y += v * h0.y; a0.z += v * h0.z; a0.w += v * h0.w;
        a1.x += v * h1.x; a1.y += v * h1.y; a1.z += v * h1.z; a1.w += v * h1.w;
    }
#pragma unroll
    for (int mm = 8; mm < 64; mm <<= 1) {
        a0.x += __shfl_xor(a0.x, mm);
        a0.y += __shfl_xor(a0.y, mm);
        a0.z += __shfl_xor(a0.z, mm);
        a0.w += __shfl_xor(a0.w, mm);
        a1.x += __shfl_xor(a1.x, mm);
        a1.y += __shfl_xor(a1.y, mm);
        a1.z += __shfl_xor(a1.z, mm);
        a1.w += __shfl_xor(a1.w, mm);
    }
    if (l < 8) {
        gc[g][16 + l] = a0;        // y2 quads 0..7
        gc[g][24 + l] = a1;        // y2 quads 8..15
    }
    if (l < 16) gc[g][l] = h4[n * 16 + l];
    __syncthreads();
    if (l < NC) {
        const float4* w4 = (const float4*)&W2[l * (2 * HID)];
        float a = b2[l];
#pragma unroll
        for (int j = 0; j < 32; ++j) {
            const float4 gv = gc[g][j];
            const float4 wv = w4[j];
            a += gv.x * wv.x + gv.y * wv.y + gv.z * wv.z + gv.w * wv.w;
        }
        out[n * NC + l] = a;
    }
}

extern "C" void kernel_launch(void* const* d_in, const int* in_sizes, int n_in,
                              void* d_out, int out_size, void* d_ws, size_t ws_size,
                              hipStream_t stream) {
    const float* x  = (const float*)d_in[0];
    const int*   ei = (const int*)d_in[1];
    const float* w  = (const float*)d_in[2];
    // d_in[3] is k (always 2)
    const float* W1 = (const float*)d_in[4];
    const float* b1 = (const float*)d_in[5];
    const float* W2 = (const float*)d_in[6];
    const float* b2 = (const float*)d_in[7];
    float* out = (float*)d_out;

    char* ws = (char*)d_ws;
    unsigned* keys = (unsigned*)(ws + (0 << 20));               // 1 MiB
    unsigned* vals = (unsigned*)(ws + (1 << 20));               // 1 MiB (contiguous with cnt)
    unsigned* cnt  = (unsigned*)(ws + (2 << 20));               // 32 KiB (contiguous after vals)
    uint2*    ell  = (uint2*)   (ws + (2 << 20) + (64 << 10));  // 6 MiB (NN*96*8B)
    float*    h    = (float*)   (ws + (9 << 20));               // 2 MiB

    const int* src = ei;        // edge_index[0, :]
    const int* dst = ei + NE;   // edge_index[1, :]

    init_tables<<<(KV4 + 255) / 256, 256, 0, stream>>>((uint4*)keys);
    build1<<<NE / 256, 256, 0, stream>>>(src, dst, w, keys, vals, cnt, ell);
    build2<<<NE / 256, 256, 0, stream>>>(src, dst, w, keys, vals, cnt, ell);
    fusedA<<<NN / 4, 256, 0, stream>>>(cnt, ell, x, W1, b1, h);
    fusedB<<<NN / 4, 256, 0, stream>>>(cnt, ell, h, W2, b2, out);
}